// Round 4
// baseline (740.032 us; speedup 1.0000x reference)
//
#include <hip/hip_runtime.h>

#define DEVI __device__ __forceinline__

typedef _Float16 h16;
typedef h16 h16x8 __attribute__((ext_vector_type(8)));
typedef h16 h16x4 __attribute__((ext_vector_type(4)));
typedef h16 h16x2 __attribute__((ext_vector_type(2)));
typedef float f32x4 __attribute__((ext_vector_type(4)));
typedef unsigned short u16;
typedef u16 u16x8 __attribute__((ext_vector_type(8)));
typedef u16 u16x4 __attribute__((ext_vector_type(4)));

constexpr int Bc = 2, Sc = 2048, Dc = 2048, HQc = 32, HKVc = 8, HDc = 64;

DEVI u16 f2h(float f){ h16 h = (h16)f; return __builtin_bit_cast(u16, h); }
DEVI float h2f(u16 u){ return (float)__builtin_bit_cast(h16, u); }
DEVI h16x2 pkrtz(float a, float b){ return __builtin_bit_cast(h16x2, __builtin_amdgcn_cvt_pkrtz(a, b)); }

DEVI f32x4 mfma32(h16x8 a, h16x8 b, f32x4 c){ return __builtin_amdgcn_mfma_f32_16x16x32_f16(a, b, c, 0, 0, 0); }
DEVI f32x4 mfma16(h16x4 a, h16x4 b, f32x4 c){ return __builtin_amdgcn_mfma_f32_16x16x16f16(a, b, c, 0, 0, 0); }

DEVI void glds16(const void* g, void* l){
  __builtin_amdgcn_global_load_lds((__attribute__((address_space(1))) void*)g,
                                   (__attribute__((address_space(3))) void*)l, 16, 0, 0);
}

// ---------------- 1. convert x fp32 -> fp16 ----------------
__global__ __launch_bounds__(256) void convert_x(const float* __restrict__ src, u16* __restrict__ dst){
  size_t i = ((size_t)blockIdx.x * 256 + threadIdx.x) * 8;
  f32x4 a = *(const f32x4*)(src + i);
  f32x4 b = *(const f32x4*)(src + i + 4);
  u16x8 o;
  #pragma unroll
  for (int j = 0; j < 4; ++j){ o[j] = f2h(a[j]); o[4+j] = f2h(b[j]); }
  *(u16x8*)(dst + i) = o;
}

// ---------------- 2. transpose + convert weights: [K][N] f32 -> [N][K] f16 ----------------
__global__ __launch_bounds__(256) void transpose_w(const float* __restrict__ wq, const float* __restrict__ wk,
                                                   const float* __restrict__ wv, const float* __restrict__ wo,
                                                   u16* __restrict__ wqT, u16* __restrict__ wkT,
                                                   u16* __restrict__ wvT, u16* __restrict__ woT){
  __shared__ float tile[32][33];
  int z = blockIdx.z;
  const float* src = (z==0) ? wq : (z==1) ? wk : (z==2) ? wv : wo;
  u16* dst         = (z==0) ? wqT : (z==1) ? wkT : (z==2) ? wvT : woT;
  int N = (z==0 || z==3) ? 2048 : 512;
  int n0 = blockIdx.x * 32;
  if (n0 >= N) return;
  int k0 = blockIdx.y * 32;
  int tx = threadIdx.x, ty = threadIdx.y;
  #pragma unroll
  for (int i = 0; i < 4; ++i)
    tile[ty + i*8][tx] = src[(size_t)(k0 + ty + i*8) * N + n0 + tx];
  __syncthreads();
  #pragma unroll
  for (int i = 0; i < 4; ++i){
    int nn = ty + i*8;
    dst[(size_t)(n0 + nn) * 2048 + k0 + tx] = f2h(tile[tx][nn]);
  }
}

// ---------------- 3/6. GEMM: C[4096 x N] = A[4096 x 2048] @ W^T rows ----------------
template<int MODE>
__global__ __launch_bounds__(256) void gemm_k(const u16* __restrict__ A,
    const u16* __restrict__ W0, const u16* __restrict__ W1, const u16* __restrict__ W2,
    u16* __restrict__ Qb, u16* __restrict__ Kb, u16* __restrict__ Vb, float* __restrict__ Out){
  __shared__ u16 ldsA[128 * 64];
  __shared__ u16 ldsB[128 * 64];
  int tid = threadIdx.x, wv_ = tid >> 6, l = tid & 63, t = l & 15, g = l >> 4;
  int wm = wv_ >> 1, wn = wv_ & 1;
  int m0 = blockIdx.y * 128, n0 = blockIdx.x * 128;
  const u16* Wt; int n0l; int matid;
  if (MODE == 1){ Wt = W0; n0l = n0; matid = 0; }
  else {
    if (n0 < 2048)      { Wt = W0; n0l = n0;        matid = 0; }
    else if (n0 < 2560) { Wt = W1; n0l = n0 - 2048; matid = 1; }
    else                { Wt = W2; n0l = n0 - 2560; matid = 2; }
  }
  f32x4 acc[4][4] = {};
  int lr = l >> 3, lc = l & 7;
  for (int kk = 0; kk < 32; ++kk){
    int k0 = kk * 64;
    #pragma unroll
    for (int i = 0; i < 4; ++i){
      int row = wv_ * 32 + i * 8 + lr;
      int ca = lc ^ (row & 7);            // pre-swizzled global source (rule 21)
      glds16(A  + (size_t)(m0  + row) * 2048 + k0 + ca * 8, &ldsA[(wv_*32 + i*8) * 64]);
      glds16(Wt + (size_t)(n0l + row) * 2048 + k0 + ca * 8, &ldsB[(wv_*32 + i*8) * 64]);
    }
    __syncthreads();
    #pragma unroll
    for (int kf = 0; kf < 2; ++kf){
      h16x8 af[4], bf[4];
      #pragma unroll
      for (int mb = 0; mb < 4; ++mb){
        int r = wm*64 + mb*16 + t;
        af[mb] = *(const h16x8*)&ldsA[r*64 + ((((kf<<2)|g) ^ (r&7)) << 3)];
      }
      #pragma unroll
      for (int nb = 0; nb < 4; ++nb){
        int r = wn*64 + nb*16 + t;
        bf[nb] = *(const h16x8*)&ldsB[r*64 + ((((kf<<2)|g) ^ (r&7)) << 3)];
      }
      #pragma unroll
      for (int mb = 0; mb < 4; ++mb)
        #pragma unroll
        for (int nb = 0; nb < 4; ++nb)
          acc[mb][nb] = mfma32(af[mb], bf[nb], acc[mb][nb]);
    }
    __syncthreads();
  }
  if (MODE == 0){
    #pragma unroll
    for (int mb = 0; mb < 4; ++mb){
      int mrow = m0 + wm*64 + mb*16 + (g << 2);
      #pragma unroll
      for (int nb = 0; nb < 4; ++nb){
        int col = n0l + wn*64 + nb*16 + t;
        int h = col >> 6, d = col & 63;
        #pragma unroll
        for (int r = 0; r < 4; ++r){
          int m = mrow + r;
          int bb = m >> 11, s = m & 2047;
          u16 v = f2h(acc[mb][nb][r]);
          if (matid == 0)      Qb[(((size_t)bb*HQc  + h)*Sc + s)*HDc + d] = v;
          else if (matid == 1) Kb[(((size_t)bb*HKVc + h)*Sc + s)*HDc + d] = v;
          else                 Vb[(((size_t)bb*HKVc + h)*Sc + s)*HDc + d] = v;
        }
      }
    }
  } else {
    #pragma unroll
    for (int mb = 0; mb < 4; ++mb){
      int mrow = m0 + wm*64 + mb*16 + (g << 2);
      #pragma unroll
      for (int nb = 0; nb < 4; ++nb){
        int col = n0 + wn*64 + nb*16 + t;
        #pragma unroll
        for (int r = 0; r < 4; ++r)
          Out[(size_t)(mrow + r) * 2048 + col] = acc[mb][nb][r];
      }
    }
  }
}

// ---------------- 4. RoPE on Q and K; folds 1/8 * LOG2E into Q (softmax done in base-2) ----------------
__global__ __launch_bounds__(256) void rope_k(u16* __restrict__ Qb, u16* __restrict__ Kb,
                                              const float* __restrict__ fcos, const float* __restrict__ fsin){
  int gid = blockIdx.x * 256 + threadIdx.x;
  int row = gid >> 3, seg = gid & 7;
  u16* p; float scale; int s;
  if (row < Bc*HQc*Sc){ p = Qb + (size_t)row*HDc + seg*8; s = row & (Sc-1); scale = 0.125f * 1.44269504f; }
  else { int r2 = row - Bc*HQc*Sc; p = Kb + (size_t)r2*HDc + seg*8; s = r2 & (Sc-1); scale = 1.0f; }
  u16x8 u = *(u16x8*)p;
  const float* cp = fcos + s*32 + seg*4;
  const float* sp = fsin + s*32 + seg*4;
  u16x8 o;
  #pragma unroll
  for (int i = 0; i < 4; ++i){
    float xr = h2f(u[2*i]), xi = h2f(u[2*i+1]);
    float c = cp[i], sn = sp[i];
    o[2*i]   = f2h((xr*c - xi*sn) * scale);
    o[2*i+1] = f2h((xr*sn + xi*c) * scale);
  }
  *(u16x8*)p = o;
}

// ---------------- 5. causal GQA flash attention ----------------
// Grid 2048 = (32 qb DESCENDING, 64 head) -> 8 blocks/CU resident (VGPR<=64 via launch_bounds),
// heavy blocks dispatch first so the unbalanced tail vanishes under 264 avg iter/CU.
// 4 waves x 16 q-rows (64-q tile), kv tile = 32, double-buffered V^T (stride 34), ONE barrier/iter.
// Swapped QK^T: S^T = mfma32(K, Q) -> lane (g,t) holds 8 kv-scores for q-col t.
// PV: O^T = V^T @ P^T via mfma16; B-frag == lane's own P regs. Scores arrive in log2 units.
// l_run kept as PER-LANE partial (alpha is g-uniform) -> no sum-shuffles in the loop.
__global__ __launch_bounds__(256, 8) void attn_k(const u16* __restrict__ Qb, const u16* __restrict__ Kb,
                                                 const u16* __restrict__ Vb, u16* __restrict__ Ob){
  __shared__ u16 vlds[2][64 * 34];
  int tid = threadIdx.x, w = tid >> 6, l = tid & 63, t = l & 15, g = l >> 4;
  int qb = 31 - blockIdx.x, head = blockIdx.y;
  int b = head >> 5, hq = head & 31, hkv = hq >> 2;
  const u16* Kp = Kb + ((size_t)(b*HKVc + hkv)) * Sc * HDc;
  const u16* Vp = Vb + ((size_t)(b*HKVc + hkv)) * Sc * HDc;
  int kv2 = tid >> 4, dseg = tid & 15;   // V staging: thread -> (kv pair, 4-elem d group)

  int q0 = qb * 64, nt = 2*qb + 2;
  int qrow = q0 + w*16 + t;
  const u16* Qp = Qb + (((size_t)(b*HQc + hq))*Sc + qrow) * HDc;
  h16x8 qf0 = *(const h16x8*)(Qp + g*8);
  h16x8 qf1 = *(const h16x8*)(Qp + 32 + g*8);
  f32x4 o[4] = {};
  float m_run = -1e30f, l_run = 0.0f;

  { // prologue: stage V tile 0 -> vlds[0]  (V^T, paired u32 writes, 2-way free)
    u16x4 a = *(const u16x4*)(Vp + (size_t)(2*kv2    )*HDc + dseg*4);
    u16x4 c = *(const u16x4*)(Vp + (size_t)(2*kv2 + 1)*HDc + dseg*4);
    #pragma unroll
    for (int e = 0; e < 4; ++e){
      unsigned pk = (unsigned)a[e] | ((unsigned)c[e] << 16);
      *(unsigned*)&vlds[0][(dseg*4 + e)*34 + 2*kv2] = pk;
    }
  }
  __syncthreads();

  #pragma unroll 1
  for (int tt = 0; tt < nt; ++tt){
    int kv0 = tt * 32, cur = tt & 1;
    bool have = (tt + 1 < nt);
    u16x4 nv0, nv1;
    if (have){ // issue next V loads early (hide under QK/softmax)
      nv0 = *(const u16x4*)(Vp + (size_t)(kv0 + 32 + 2*kv2)*HDc + dseg*4);
      nv1 = *(const u16x4*)(Vp + (size_t)(kv0 + 33 + 2*kv2)*HDc + dseg*4);
    }
    // K fragments direct from global (L2-resident: 256 KB/head)
    h16x8 ka00 = *(const h16x8*)(Kp + (size_t)(kv0      + t)*HDc +      g*8);
    h16x8 ka01 = *(const h16x8*)(Kp + (size_t)(kv0      + t)*HDc + 32 + g*8);
    h16x8 ka10 = *(const h16x8*)(Kp + (size_t)(kv0 + 16 + t)*HDc +      g*8);
    h16x8 ka11 = *(const h16x8*)(Kp + (size_t)(kv0 + 16 + t)*HDc + 32 + g*8);
    f32x4 s0 = {}, s1 = {};
    s0 = mfma32(ka00, qf0, s0); s0 = mfma32(ka01, qf1, s0);
    s1 = mfma32(ka10, qf0, s1); s1 = mfma32(ka11, qf1, s1);

    float p0[4], p1[4];
    if (tt >= 2*qb){ // diagonal tiles: mask
      #pragma unroll
      for (int r = 0; r < 4; ++r){
        p0[r] = (kv0      + (g<<2) + r <= qrow) ? s0[r] : -1e30f;
        p1[r] = (kv0 + 16 + (g<<2) + r <= qrow) ? s1[r] : -1e30f;
      }
    } else {
      #pragma unroll
      for (int r = 0; r < 4; ++r){ p0[r] = s0[r]; p1[r] = s1[r]; }
    }
    float mt = fmaxf(fmaxf(fmaxf(p0[0],p0[1]), fmaxf(p0[2],p0[3])),
                     fmaxf(fmaxf(p1[0],p1[1]), fmaxf(p1[2],p1[3])));
    mt = fmaxf(mt, __shfl_xor(mt, 16));
    mt = fmaxf(mt, __shfl_xor(mt, 32));
    if (!__all(mt <= m_run + 8.0f)){   // T13 defer-rescale
      float m_new = fmaxf(m_run, mt);
      float alpha = exp2f(m_run - m_new);
      l_run *= alpha;
      #pragma unroll
      for (int db = 0; db < 4; ++db)
        #pragma unroll
        for (int r = 0; r < 4; ++r) o[db][r] *= alpha;
      m_run = m_new;
    }
    #pragma unroll
    for (int r = 0; r < 4; ++r){ p0[r] = exp2f(p0[r] - m_run); l_run += p0[r]; }
    #pragma unroll
    for (int r = 0; r < 4; ++r){ p1[r] = exp2f(p1[r] - m_run); l_run += p1[r]; }

    if (have){ // stage next V -> vlds[cur^1] (PV below reads vlds[cur]; no race)
      #pragma unroll
      for (int e = 0; e < 4; ++e){
        unsigned pk = (unsigned)nv0[e] | ((unsigned)nv1[e] << 16);
        *(unsigned*)&vlds[cur^1][(dseg*4 + e)*34 + 2*kv2] = pk;
      }
    }

    h16x2 c0 = pkrtz(p0[0], p0[1]);
    h16x2 c1 = pkrtz(p0[2], p0[3]);
    h16x2 c2 = pkrtz(p1[0], p1[1]);
    h16x2 c3 = pkrtz(p1[2], p1[3]);
    h16x4 pf0 = {c0[0], c0[1], c1[0], c1[1]};
    h16x4 pf1 = {c2[0], c2[1], c3[0], c3[1]};
    #pragma unroll
    for (int db = 0; db < 4; ++db){
      const u16* vp = &vlds[cur][(db*16 + t)*34 + (g<<2)];
      h16x4 vf0 = *(const h16x4*)vp;
      h16x4 vf1 = *(const h16x4*)(vp + 16);
      o[db] = mfma16(vf0, pf0, o[db]);     // kv 0..15 of tile
      o[db] = mfma16(vf1, pf1, o[db]);     // kv 16..31
    }
    __syncthreads();
  }

  // final cross-g reduce of the per-lane l partials
  l_run += __shfl_xor(l_run, 16);
  l_run += __shfl_xor(l_run, 32);
  float inv = 1.0f / l_run;
  u16* Op = Ob + ((size_t)(b*Sc + qrow)) * Dc + hq*HDc;
  #pragma unroll
  for (int db = 0; db < 4; ++db){
    u16x4 st;
    #pragma unroll
    for (int r = 0; r < 4; ++r) st[r] = f2h(o[db][r] * inv);
    *(u16x4*)(Op + db*16 + (g<<2)) = st;
  }
}

// ---------------- launch ----------------
extern "C" void kernel_launch(void* const* d_in, const int* in_sizes, int n_in,
                              void* d_out, int out_size, void* d_ws, size_t ws_size,
                              hipStream_t stream){
  const float* x    = (const float*)d_in[0];
  const float* fcos = (const float*)d_in[1];
  const float* fsin = (const float*)d_in[2];
  const float* wq   = (const float*)d_in[3];
  const float* wk   = (const float*)d_in[4];
  const float* wv   = (const float*)d_in[5];
  const float* wo   = (const float*)d_in[6];
  float* out = (float*)d_out;

  u16* ws  = (u16*)d_ws;
  u16* x16 = ws;                    // 8,388,608  (reused as attn-out Ob after gemm<0>)
  u16* wqT = x16 + 8388608;         // 4,194,304
  u16* wkT = wqT + 4194304;         // 1,048,576
  u16* wvT = wkT + 1048576;         // 1,048,576
  u16* woT = wvT + 1048576;         // 4,194,304
  u16* Qb  = woT + 4194304;         // 8,388,608
  u16* Kb  = Qb  + 8388608;         // 2,097,152
  u16* Vb  = Kb  + 2097152;         // 2,097,152
  u16* Ob  = x16;                   // alias: x16 dead after gemm<0>

  convert_x  <<<4096, 256, 0, stream>>>(x, x16);
  transpose_w<<<dim3(64,64,4), dim3(32,8), 0, stream>>>(wq, wk, wv, wo, wqT, wkT, wvT, woT);
  gemm_k<0>  <<<dim3(24,32), 256, 0, stream>>>(x16, wqT, wkT, wvT, Qb, Kb, Vb, nullptr);
  rope_k     <<<5120, 256, 0, stream>>>(Qb, Kb, fcos, fsin);
  attn_k     <<<dim3(32,64), 256, 0, stream>>>(Qb, Kb, Vb, Ob);
  gemm_k<1>  <<<dim3(16,32), 256, 0, stream>>>(Ob, woT, nullptr, nullptr, nullptr, nullptr, nullptr, out);
}

// Round 5
// 739.448 us; speedup vs baseline: 1.0008x; 1.0008x over previous
//
#include <hip/hip_runtime.h>

#define DEVI __device__ __forceinline__

typedef _Float16 h16;
typedef h16 h16x8 __attribute__((ext_vector_type(8)));
typedef h16 h16x4 __attribute__((ext_vector_type(4)));
typedef h16 h16x2 __attribute__((ext_vector_type(2)));
typedef float f32x4 __attribute__((ext_vector_type(4)));
typedef unsigned short u16;
typedef u16 u16x8 __attribute__((ext_vector_type(8)));
typedef u16 u16x4 __attribute__((ext_vector_type(4)));

constexpr int Bc = 2, Sc = 2048, Dc = 2048, HQc = 32, HKVc = 8, HDc = 64;

DEVI u16 f2h(float f){ h16 h = (h16)f; return __builtin_bit_cast(u16, h); }
DEVI float h2f(u16 u){ return (float)__builtin_bit_cast(h16, u); }
DEVI h16x2 pkrtz(float a, float b){ return __builtin_bit_cast(h16x2, __builtin_amdgcn_cvt_pkrtz(a, b)); }

DEVI f32x4 mfma32(h16x8 a, h16x8 b, f32x4 c){ return __builtin_amdgcn_mfma_f32_16x16x32_f16(a, b, c, 0, 0, 0); }
DEVI f32x4 mfma16(h16x4 a, h16x4 b, f32x4 c){ return __builtin_amdgcn_mfma_f32_16x16x16f16(a, b, c, 0, 0, 0); }

DEVI void glds16(const void* g, void* l){
  __builtin_amdgcn_global_load_lds((__attribute__((address_space(1))) void*)g,
                                   (__attribute__((address_space(3))) void*)l, 16, 0, 0);
}

// ---------------- 1. convert x fp32 -> fp16 ----------------
__global__ __launch_bounds__(256) void convert_x(const float* __restrict__ src, u16* __restrict__ dst){
  size_t i = ((size_t)blockIdx.x * 256 + threadIdx.x) * 8;
  f32x4 a = *(const f32x4*)(src + i);
  f32x4 b = *(const f32x4*)(src + i + 4);
  u16x8 o;
  #pragma unroll
  for (int j = 0; j < 4; ++j){ o[j] = f2h(a[j]); o[4+j] = f2h(b[j]); }
  *(u16x8*)(dst + i) = o;
}

// ---------------- 2. transpose + convert weights: [K][N] f32 -> [N][K] f16 ----------------
__global__ __launch_bounds__(256) void transpose_w(const float* __restrict__ wq, const float* __restrict__ wk,
                                                   const float* __restrict__ wv, const float* __restrict__ wo,
                                                   u16* __restrict__ wqT, u16* __restrict__ wkT,
                                                   u16* __restrict__ wvT, u16* __restrict__ woT){
  __shared__ float tile[32][33];
  int z = blockIdx.z;
  const float* src = (z==0) ? wq : (z==1) ? wk : (z==2) ? wv : wo;
  u16* dst         = (z==0) ? wqT : (z==1) ? wkT : (z==2) ? wvT : woT;
  int N = (z==0 || z==3) ? 2048 : 512;
  int n0 = blockIdx.x * 32;
  if (n0 >= N) return;
  int k0 = blockIdx.y * 32;
  int tx = threadIdx.x, ty = threadIdx.y;
  #pragma unroll
  for (int i = 0; i < 4; ++i)
    tile[ty + i*8][tx] = src[(size_t)(k0 + ty + i*8) * N + n0 + tx];
  __syncthreads();
  #pragma unroll
  for (int i = 0; i < 4; ++i){
    int nn = ty + i*8;
    dst[(size_t)(n0 + nn) * 2048 + k0 + tx] = f2h(tile[tx][nn]);
  }
}

// ---------------- 3/6. GEMM: C[4096 x N] = A[4096 x 2048] @ W^T rows ----------------
template<int MODE>
__global__ __launch_bounds__(256) void gemm_k(const u16* __restrict__ A,
    const u16* __restrict__ W0, const u16* __restrict__ W1, const u16* __restrict__ W2,
    u16* __restrict__ Qb, u16* __restrict__ Kb, u16* __restrict__ Vb, float* __restrict__ Out){
  __shared__ u16 ldsA[128 * 64];
  __shared__ u16 ldsB[128 * 64];
  int tid = threadIdx.x, wv_ = tid >> 6, l = tid & 63, t = l & 15, g = l >> 4;
  int wm = wv_ >> 1, wn = wv_ & 1;
  int m0 = blockIdx.y * 128, n0 = blockIdx.x * 128;
  const u16* Wt; int n0l; int matid;
  if (MODE == 1){ Wt = W0; n0l = n0; matid = 0; }
  else {
    if (n0 < 2048)      { Wt = W0; n0l = n0;        matid = 0; }
    else if (n0 < 2560) { Wt = W1; n0l = n0 - 2048; matid = 1; }
    else                { Wt = W2; n0l = n0 - 2560; matid = 2; }
  }
  f32x4 acc[4][4] = {};
  int lr = l >> 3, lc = l & 7;
  for (int kk = 0; kk < 32; ++kk){
    int k0 = kk * 64;
    #pragma unroll
    for (int i = 0; i < 4; ++i){
      int row = wv_ * 32 + i * 8 + lr;
      int ca = lc ^ (row & 7);            // pre-swizzled global source (rule 21)
      glds16(A  + (size_t)(m0  + row) * 2048 + k0 + ca * 8, &ldsA[(wv_*32 + i*8) * 64]);
      glds16(Wt + (size_t)(n0l + row) * 2048 + k0 + ca * 8, &ldsB[(wv_*32 + i*8) * 64]);
    }
    __syncthreads();
    #pragma unroll
    for (int kf = 0; kf < 2; ++kf){
      h16x8 af[4], bf[4];
      #pragma unroll
      for (int mb = 0; mb < 4; ++mb){
        int r = wm*64 + mb*16 + t;
        af[mb] = *(const h16x8*)&ldsA[r*64 + ((((kf<<2)|g) ^ (r&7)) << 3)];
      }
      #pragma unroll
      for (int nb = 0; nb < 4; ++nb){
        int r = wn*64 + nb*16 + t;
        bf[nb] = *(const h16x8*)&ldsB[r*64 + ((((kf<<2)|g) ^ (r&7)) << 3)];
      }
      #pragma unroll
      for (int mb = 0; mb < 4; ++mb)
        #pragma unroll
        for (int nb = 0; nb < 4; ++nb)
          acc[mb][nb] = mfma32(af[mb], bf[nb], acc[mb][nb]);
    }
    __syncthreads();
  }
  if (MODE == 0){
    #pragma unroll
    for (int mb = 0; mb < 4; ++mb){
      int mrow = m0 + wm*64 + mb*16 + (g << 2);
      #pragma unroll
      for (int nb = 0; nb < 4; ++nb){
        int col = n0l + wn*64 + nb*16 + t;
        int h = col >> 6, d = col & 63;
        #pragma unroll
        for (int r = 0; r < 4; ++r){
          int m = mrow + r;
          int bb = m >> 11, s = m & 2047;
          u16 v = f2h(acc[mb][nb][r]);
          if (matid == 0)      Qb[(((size_t)bb*HQc  + h)*Sc + s)*HDc + d] = v;
          else if (matid == 1) Kb[(((size_t)bb*HKVc + h)*Sc + s)*HDc + d] = v;
          else                 Vb[(((size_t)bb*HKVc + h)*Sc + s)*HDc + d] = v;
        }
      }
    }
  } else {
    #pragma unroll
    for (int mb = 0; mb < 4; ++mb){
      int mrow = m0 + wm*64 + mb*16 + (g << 2);
      #pragma unroll
      for (int nb = 0; nb < 4; ++nb){
        int col = n0 + wn*64 + nb*16 + t;
        #pragma unroll
        for (int r = 0; r < 4; ++r)
          Out[(size_t)(mrow + r) * 2048 + col] = acc[mb][nb][r];
      }
    }
  }
}

// ---------------- 4. RoPE on Q and K; folds 1/8 * LOG2E into Q (softmax done in base-2) ----------------
__global__ __launch_bounds__(256) void rope_k(u16* __restrict__ Qb, u16* __restrict__ Kb,
                                              const float* __restrict__ fcos, const float* __restrict__ fsin){
  int gid = blockIdx.x * 256 + threadIdx.x;
  int row = gid >> 3, seg = gid & 7;
  u16* p; float scale; int s;
  if (row < Bc*HQc*Sc){ p = Qb + (size_t)row*HDc + seg*8; s = row & (Sc-1); scale = 0.125f * 1.44269504f; }
  else { int r2 = row - Bc*HQc*Sc; p = Kb + (size_t)r2*HDc + seg*8; s = r2 & (Sc-1); scale = 1.0f; }
  u16x8 u = *(u16x8*)p;
  const float* cp = fcos + s*32 + seg*4;
  const float* sp = fsin + s*32 + seg*4;
  u16x8 o;
  #pragma unroll
  for (int i = 0; i < 4; ++i){
    float xr = h2f(u[2*i]), xi = h2f(u[2*i+1]);
    float c = cp[i], sn = sp[i];
    o[2*i]   = f2h((xr*c - xi*sn) * scale);
    o[2*i+1] = f2h((xr*sn + xi*c) * scale);
  }
  *(u16x8*)p = o;
}

// ---------------- 5. causal GQA flash attention ----------------
// Grid 2048 = (32 qb DESCENDING, 64 head); natural VGPR budget (NO min-waves clamp:
// R4 showed launch_bounds(256,8) forces VGPR 48->32 and spills; at VGPR~48 the
// 32-waves/CU cap itself allows 8 blocks/CU). Heavy blocks dispatch first.
// 4 waves x 16 q-rows (64-q tile), kv tile = 32, double-buffered V^T (stride 34), ONE barrier/iter.
// Swapped QK^T: S^T = mfma32(K, Q) -> lane (g,t) holds 8 kv-scores for q-col t.
// PV: O^T = V^T @ P^T via mfma16; B-frag == lane's own P regs. Scores arrive in log2 units.
// l_run kept as PER-LANE partial (alpha is g-uniform) -> no sum-shuffles in the loop.
__global__ __launch_bounds__(256) void attn_k(const u16* __restrict__ Qb, const u16* __restrict__ Kb,
                                              const u16* __restrict__ Vb, u16* __restrict__ Ob){
  __shared__ u16 vlds[2][64 * 34];
  int tid = threadIdx.x, w = tid >> 6, l = tid & 63, t = l & 15, g = l >> 4;
  int qb = 31 - blockIdx.x, head = blockIdx.y;
  int b = head >> 5, hq = head & 31, hkv = hq >> 2;
  const u16* Kp = Kb + ((size_t)(b*HKVc + hkv)) * Sc * HDc;
  const u16* Vp = Vb + ((size_t)(b*HKVc + hkv)) * Sc * HDc;
  int kv2 = tid >> 4, dseg = tid & 15;   // V staging: thread -> (kv pair, 4-elem d group)

  int q0 = qb * 64, nt = 2*qb + 2;
  int qrow = q0 + w*16 + t;
  const u16* Qp = Qb + (((size_t)(b*HQc + hq))*Sc + qrow) * HDc;
  h16x8 qf0 = *(const h16x8*)(Qp + g*8);
  h16x8 qf1 = *(const h16x8*)(Qp + 32 + g*8);
  f32x4 o[4] = {};
  float m_run = -1e30f, l_run = 0.0f;

  { // prologue: stage V tile 0 -> vlds[0]  (V^T, paired u32 writes, 2-way free)
    u16x4 a = *(const u16x4*)(Vp + (size_t)(2*kv2    )*HDc + dseg*4);
    u16x4 c = *(const u16x4*)(Vp + (size_t)(2*kv2 + 1)*HDc + dseg*4);
    #pragma unroll
    for (int e = 0; e < 4; ++e){
      unsigned pk = (unsigned)a[e] | ((unsigned)c[e] << 16);
      *(unsigned*)&vlds[0][(dseg*4 + e)*34 + 2*kv2] = pk;
    }
  }
  __syncthreads();

  #pragma unroll 1
  for (int tt = 0; tt < nt; ++tt){
    int kv0 = tt * 32, cur = tt & 1;
    bool have = (tt + 1 < nt);
    u16x4 nv0, nv1;
    if (have){ // issue next V loads early (hide under QK/softmax)
      nv0 = *(const u16x4*)(Vp + (size_t)(kv0 + 32 + 2*kv2)*HDc + dseg*4);
      nv1 = *(const u16x4*)(Vp + (size_t)(kv0 + 33 + 2*kv2)*HDc + dseg*4);
    }
    // K fragments direct from global (L2-resident: 256 KB/head)
    h16x8 ka00 = *(const h16x8*)(Kp + (size_t)(kv0      + t)*HDc +      g*8);
    h16x8 ka01 = *(const h16x8*)(Kp + (size_t)(kv0      + t)*HDc + 32 + g*8);
    h16x8 ka10 = *(const h16x8*)(Kp + (size_t)(kv0 + 16 + t)*HDc +      g*8);
    h16x8 ka11 = *(const h16x8*)(Kp + (size_t)(kv0 + 16 + t)*HDc + 32 + g*8);
    f32x4 s0 = {}, s1 = {};
    s0 = mfma32(ka00, qf0, s0); s0 = mfma32(ka01, qf1, s0);
    s1 = mfma32(ka10, qf0, s1); s1 = mfma32(ka11, qf1, s1);

    float p0[4], p1[4];
    if (tt >= 2*qb){ // diagonal tiles: mask
      #pragma unroll
      for (int r = 0; r < 4; ++r){
        p0[r] = (kv0      + (g<<2) + r <= qrow) ? s0[r] : -1e30f;
        p1[r] = (kv0 + 16 + (g<<2) + r <= qrow) ? s1[r] : -1e30f;
      }
    } else {
      #pragma unroll
      for (int r = 0; r < 4; ++r){ p0[r] = s0[r]; p1[r] = s1[r]; }
    }
    float mt = fmaxf(fmaxf(fmaxf(p0[0],p0[1]), fmaxf(p0[2],p0[3])),
                     fmaxf(fmaxf(p1[0],p1[1]), fmaxf(p1[2],p1[3])));
    mt = fmaxf(mt, __shfl_xor(mt, 16));
    mt = fmaxf(mt, __shfl_xor(mt, 32));
    if (!__all(mt <= m_run + 8.0f)){   // T13 defer-rescale
      float m_new = fmaxf(m_run, mt);
      float alpha = exp2f(m_run - m_new);
      l_run *= alpha;
      #pragma unroll
      for (int db = 0; db < 4; ++db)
        #pragma unroll
        for (int r = 0; r < 4; ++r) o[db][r] *= alpha;
      m_run = m_new;
    }
    #pragma unroll
    for (int r = 0; r < 4; ++r){ p0[r] = exp2f(p0[r] - m_run); l_run += p0[r]; }
    #pragma unroll
    for (int r = 0; r < 4; ++r){ p1[r] = exp2f(p1[r] - m_run); l_run += p1[r]; }

    if (have){ // stage next V -> vlds[cur^1] (PV below reads vlds[cur]; no race)
      #pragma unroll
      for (int e = 0; e < 4; ++e){
        unsigned pk = (unsigned)nv0[e] | ((unsigned)nv1[e] << 16);
        *(unsigned*)&vlds[cur^1][(dseg*4 + e)*34 + 2*kv2] = pk;
      }
    }

    h16x2 c0 = pkrtz(p0[0], p0[1]);
    h16x2 c1 = pkrtz(p0[2], p0[3]);
    h16x2 c2 = pkrtz(p1[0], p1[1]);
    h16x2 c3 = pkrtz(p1[2], p1[3]);
    h16x4 pf0 = {c0[0], c0[1], c1[0], c1[1]};
    h16x4 pf1 = {c2[0], c2[1], c3[0], c3[1]};
    #pragma unroll
    for (int db = 0; db < 4; ++db){
      const u16* vp = &vlds[cur][(db*16 + t)*34 + (g<<2)];
      h16x4 vf0 = *(const h16x4*)vp;
      h16x4 vf1 = *(const h16x4*)(vp + 16);
      o[db] = mfma16(vf0, pf0, o[db]);     // kv 0..15 of tile
      o[db] = mfma16(vf1, pf1, o[db]);     // kv 16..31
    }
    __syncthreads();
  }

  // final cross-g reduce of the per-lane l partials
  l_run += __shfl_xor(l_run, 16);
  l_run += __shfl_xor(l_run, 32);
  float inv = 1.0f / l_run;
  u16* Op = Ob + ((size_t)(b*Sc + qrow)) * Dc + hq*HDc;
  #pragma unroll
  for (int db = 0; db < 4; ++db){
    u16x4 st;
    #pragma unroll
    for (int r = 0; r < 4; ++r) st[r] = f2h(o[db][r] * inv);
    *(u16x4*)(Op + db*16 + (g<<2)) = st;
  }
}

// ---------------- launch ----------------
extern "C" void kernel_launch(void* const* d_in, const int* in_sizes, int n_in,
                              void* d_out, int out_size, void* d_ws, size_t ws_size,
                              hipStream_t stream){
  const float* x    = (const float*)d_in[0];
  const float* fcos = (const float*)d_in[1];
  const float* fsin = (const float*)d_in[2];
  const float* wq   = (const float*)d_in[3];
  const float* wk   = (const float*)d_in[4];
  const float* wv   = (const float*)d_in[5];
  const float* wo   = (const float*)d_in[6];
  float* out = (float*)d_out;

  u16* ws  = (u16*)d_ws;
  u16* x16 = ws;                    // 8,388,608  (reused as attn-out Ob after gemm<0>)
  u16* wqT = x16 + 8388608;         // 4,194,304
  u16* wkT = wqT + 4194304;         // 1,048,576
  u16* wvT = wkT + 1048576;         // 1,048,576
  u16* woT = wvT + 1048576;         // 4,194,304
  u16* Qb  = woT + 4194304;         // 8,388,608
  u16* Kb  = Qb  + 8388608;         // 2,097,152
  u16* Vb  = Kb  + 2097152;         // 2,097,152
  u16* Ob  = x16;                   // alias: x16 dead after gemm<0>

  convert_x  <<<4096, 256, 0, stream>>>(x, x16);
  transpose_w<<<dim3(64,64,4), dim3(32,8), 0, stream>>>(wq, wk, wv, wo, wqT, wkT, wvT, woT);
  gemm_k<0>  <<<dim3(24,32), 256, 0, stream>>>(x16, wqT, wkT, wvT, Qb, Kb, Vb, nullptr);
  rope_k     <<<5120, 256, 0, stream>>>(Qb, Kb, fcos, fsin);
  attn_k     <<<dim3(32,64), 256, 0, stream>>>(Qb, Kb, Vb, Ob);
  gemm_k<1>  <<<dim3(16,32), 256, 0, stream>>>(Ob, woT, nullptr, nullptr, nullptr, nullptr, nullptr, out);
}

// Round 6
// 506.494 us; speedup vs baseline: 1.4611x; 1.4599x over previous
//
#include <hip/hip_runtime.h>

#define DEVI __device__ __forceinline__

typedef _Float16 h16;
typedef h16 h16x8 __attribute__((ext_vector_type(8)));
typedef h16 h16x4 __attribute__((ext_vector_type(4)));
typedef h16 h16x2 __attribute__((ext_vector_type(2)));
typedef float f32x4 __attribute__((ext_vector_type(4)));
typedef unsigned short u16;
typedef u16 u16x8 __attribute__((ext_vector_type(8)));
typedef u16 u16x4 __attribute__((ext_vector_type(4)));

constexpr int Bc = 2, Sc = 2048, Dc = 2048, HQc = 32, HKVc = 8, HDc = 64;

DEVI u16 f2h(float f){ h16 h = (h16)f; return __builtin_bit_cast(u16, h); }
DEVI float h2f(u16 u){ return (float)__builtin_bit_cast(h16, u); }
DEVI h16x2 pkrtz(float a, float b){ return __builtin_bit_cast(h16x2, __builtin_amdgcn_cvt_pkrtz(a, b)); }

DEVI f32x4 mfma32(h16x8 a, h16x8 b, f32x4 c){ return __builtin_amdgcn_mfma_f32_16x16x32_f16(a, b, c, 0, 0, 0); }
DEVI f32x4 mfma16(h16x4 a, h16x4 b, f32x4 c){ return __builtin_amdgcn_mfma_f32_16x16x16f16(a, b, c, 0, 0, 0); }

DEVI void glds16(const void* g, void* l){
  __builtin_amdgcn_global_load_lds((__attribute__((address_space(1))) void*)g,
                                   (__attribute__((address_space(3))) void*)l, 16, 0, 0);
}

// ---------------- 1. convert x fp32 -> fp16 ----------------
__global__ __launch_bounds__(256) void convert_x(const float* __restrict__ src, u16* __restrict__ dst){
  size_t i = ((size_t)blockIdx.x * 256 + threadIdx.x) * 8;
  f32x4 a = *(const f32x4*)(src + i);
  f32x4 b = *(const f32x4*)(src + i + 4);
  u16x8 o;
  #pragma unroll
  for (int j = 0; j < 4; ++j){ o[j] = f2h(a[j]); o[4+j] = f2h(b[j]); }
  *(u16x8*)(dst + i) = o;
}

// ---------------- 2. transpose + convert weights: [K][N] f32 -> [N][K] f16 ----------------
__global__ __launch_bounds__(256) void transpose_w(const float* __restrict__ wq, const float* __restrict__ wk,
                                                   const float* __restrict__ wv, const float* __restrict__ wo,
                                                   u16* __restrict__ wqT, u16* __restrict__ wkT,
                                                   u16* __restrict__ wvT, u16* __restrict__ woT){
  __shared__ float tile[32][33];
  int z = blockIdx.z;
  const float* src = (z==0) ? wq : (z==1) ? wk : (z==2) ? wv : wo;
  u16* dst         = (z==0) ? wqT : (z==1) ? wkT : (z==2) ? wvT : woT;
  int N = (z==0 || z==3) ? 2048 : 512;
  int n0 = blockIdx.x * 32;
  if (n0 >= N) return;
  int k0 = blockIdx.y * 32;
  int tx = threadIdx.x, ty = threadIdx.y;
  #pragma unroll
  for (int i = 0; i < 4; ++i)
    tile[ty + i*8][tx] = src[(size_t)(k0 + ty + i*8) * N + n0 + tx];
  __syncthreads();
  #pragma unroll
  for (int i = 0; i < 4; ++i){
    int nn = ty + i*8;
    dst[(size_t)(n0 + nn) * 2048 + k0 + tx] = f2h(tile[tx][nn]);
  }
}

// ---------------- 3/6. GEMM: C[4096 x N] = A[4096 x 2048] @ W^T rows ----------------
template<int MODE>
__global__ __launch_bounds__(256) void gemm_k(const u16* __restrict__ A,
    const u16* __restrict__ W0, const u16* __restrict__ W1, const u16* __restrict__ W2,
    u16* __restrict__ Qb, u16* __restrict__ Kb, u16* __restrict__ Vb, float* __restrict__ Out){
  __shared__ u16 ldsA[128 * 64];
  __shared__ u16 ldsB[128 * 64];
  int tid = threadIdx.x, wv_ = tid >> 6, l = tid & 63, t = l & 15, g = l >> 4;
  int wm = wv_ >> 1, wn = wv_ & 1;
  int m0 = blockIdx.y * 128, n0 = blockIdx.x * 128;
  const u16* Wt; int n0l; int matid;
  if (MODE == 1){ Wt = W0; n0l = n0; matid = 0; }
  else {
    if (n0 < 2048)      { Wt = W0; n0l = n0;        matid = 0; }
    else if (n0 < 2560) { Wt = W1; n0l = n0 - 2048; matid = 1; }
    else                { Wt = W2; n0l = n0 - 2560; matid = 2; }
  }
  f32x4 acc[4][4] = {};
  int lr = l >> 3, lc = l & 7;
  for (int kk = 0; kk < 32; ++kk){
    int k0 = kk * 64;
    #pragma unroll
    for (int i = 0; i < 4; ++i){
      int row = wv_ * 32 + i * 8 + lr;
      int ca = lc ^ (row & 7);            // pre-swizzled global source (rule 21)
      glds16(A  + (size_t)(m0  + row) * 2048 + k0 + ca * 8, &ldsA[(wv_*32 + i*8) * 64]);
      glds16(Wt + (size_t)(n0l + row) * 2048 + k0 + ca * 8, &ldsB[(wv_*32 + i*8) * 64]);
    }
    __syncthreads();
    #pragma unroll
    for (int kf = 0; kf < 2; ++kf){
      h16x8 af[4], bf[4];
      #pragma unroll
      for (int mb = 0; mb < 4; ++mb){
        int r = wm*64 + mb*16 + t;
        af[mb] = *(const h16x8*)&ldsA[r*64 + ((((kf<<2)|g) ^ (r&7)) << 3)];
      }
      #pragma unroll
      for (int nb = 0; nb < 4; ++nb){
        int r = wn*64 + nb*16 + t;
        bf[nb] = *(const h16x8*)&ldsB[r*64 + ((((kf<<2)|g) ^ (r&7)) << 3)];
      }
      #pragma unroll
      for (int mb = 0; mb < 4; ++mb)
        #pragma unroll
        for (int nb = 0; nb < 4; ++nb)
          acc[mb][nb] = mfma32(af[mb], bf[nb], acc[mb][nb]);
    }
    __syncthreads();
  }
  if (MODE == 0){
    #pragma unroll
    for (int mb = 0; mb < 4; ++mb){
      int mrow = m0 + wm*64 + mb*16 + (g << 2);
      #pragma unroll
      for (int nb = 0; nb < 4; ++nb){
        int col = n0l + wn*64 + nb*16 + t;
        int h = col >> 6, d = col & 63;
        #pragma unroll
        for (int r = 0; r < 4; ++r){
          int m = mrow + r;
          int bb = m >> 11, s = m & 2047;
          u16 v = f2h(acc[mb][nb][r]);
          if (matid == 0)      Qb[(((size_t)bb*HQc  + h)*Sc + s)*HDc + d] = v;
          else if (matid == 1) Kb[(((size_t)bb*HKVc + h)*Sc + s)*HDc + d] = v;
          else                 Vb[(((size_t)bb*HKVc + h)*Sc + s)*HDc + d] = v;
        }
      }
    }
  } else {
    #pragma unroll
    for (int mb = 0; mb < 4; ++mb){
      int mrow = m0 + wm*64 + mb*16 + (g << 2);
      #pragma unroll
      for (int nb = 0; nb < 4; ++nb){
        int col = n0 + wn*64 + nb*16 + t;
        #pragma unroll
        for (int r = 0; r < 4; ++r)
          Out[(size_t)(mrow + r) * 2048 + col] = acc[mb][nb][r];
      }
    }
  }
}

// ---------------- 4. RoPE on Q and K; folds 1/8 * LOG2E into Q (softmax done in base-2) ----------------
__global__ __launch_bounds__(256) void rope_k(u16* __restrict__ Qb, u16* __restrict__ Kb,
                                              const float* __restrict__ fcos, const float* __restrict__ fsin){
  int gid = blockIdx.x * 256 + threadIdx.x;
  int row = gid >> 3, seg = gid & 7;
  u16* p; float scale; int s;
  if (row < Bc*HQc*Sc){ p = Qb + (size_t)row*HDc + seg*8; s = row & (Sc-1); scale = 0.125f * 1.44269504f; }
  else { int r2 = row - Bc*HQc*Sc; p = Kb + (size_t)r2*HDc + seg*8; s = r2 & (Sc-1); scale = 1.0f; }
  u16x8 u = *(u16x8*)p;
  const float* cp = fcos + s*32 + seg*4;
  const float* sp = fsin + s*32 + seg*4;
  u16x8 o;
  #pragma unroll
  for (int i = 0; i < 4; ++i){
    float xr = h2f(u[2*i]), xi = h2f(u[2*i+1]);
    float c = cp[i], sn = sp[i];
    o[2*i]   = f2h((xr*c - xi*sn) * scale);
    o[2*i+1] = f2h((xr*sn + xi*c) * scale);
  }
  *(u16x8*)p = o;
}

// ---------------- 5. causal GQA flash attention ----------------
// 128-thread blocks (2 waves x 16 q-rows = QBLK 32), fold-pair scheduling:
// block (fold, head) does qb=fold then qb=63-fold -> uniform 65 iters/block,
// 2048 uniform blocks -> 16 blocks/CU = 32 waves/CU resident (LDS 139KB/CU).
// R4/R5 lesson: with x-fastest dispatch, CU c gets blocks with equal blockIdx.x,
// so per-block work MUST be uniform; fold-pair guarantees it.
// kv tile = 32, double-buffered V^T (stride 34), ONE barrier/iter.
// Swapped QK^T: S^T = mfma32(K, Q) -> lane (g,t) holds 8 kv-scores for q-col t.
// PV: O^T = V^T @ P^T via mfma16; B-frag == lane's own P regs. Scores in log2 units.
// l_run kept as PER-LANE partial (alpha is g-uniform) -> no sum-shuffles in loop.
__global__ __launch_bounds__(128) void attn_k(const u16* __restrict__ Qb, const u16* __restrict__ Kb,
                                              const u16* __restrict__ Vb, u16* __restrict__ Ob){
  __shared__ u16 vlds[2][64 * 34];
  int tid = threadIdx.x, w = tid >> 6, l = tid & 63, t = l & 15, g = l >> 4;
  int fold = blockIdx.x, head = blockIdx.y;
  int b = head >> 5, hq = head & 31, hkv = hq >> 2;
  const u16* Kp = Kb + ((size_t)(b*HKVc + hkv)) * Sc * HDc;
  const u16* Vp = Vb + ((size_t)(b*HKVc + hkv)) * Sc * HDc;
  int kvp = tid >> 4, dseg = tid & 15;   // V staging: thread -> (kv-pairs kvp,kvp+8; 4-elem d group)

  #pragma unroll 1
  for (int part = 0; part < 2; ++part){
    int qb = part ? (63 - fold) : fold;    // 32-row q tiles
    int q0 = qb * 32, nt = qb + 1;
    int qrow = q0 + w*16 + t;
    const u16* Qp = Qb + (((size_t)(b*HQc + hq))*Sc + qrow) * HDc;
    h16x8 qf0 = *(const h16x8*)(Qp + g*8);
    h16x8 qf1 = *(const h16x8*)(Qp + 32 + g*8);
    f32x4 o[4] = {};
    float m_run = -1e30f, l_run = 0.0f;

    { // prologue: stage V tile 0 -> vlds[0]  (V^T, paired u32 writes, 2-way free)
      u16x4 a0 = *(const u16x4*)(Vp + (size_t)(2*kvp     )*HDc + dseg*4);
      u16x4 a1 = *(const u16x4*)(Vp + (size_t)(2*kvp +  1)*HDc + dseg*4);
      u16x4 b0 = *(const u16x4*)(Vp + (size_t)(2*kvp + 16)*HDc + dseg*4);
      u16x4 b1 = *(const u16x4*)(Vp + (size_t)(2*kvp + 17)*HDc + dseg*4);
      #pragma unroll
      for (int e = 0; e < 4; ++e){
        *(unsigned*)&vlds[0][(dseg*4 + e)*34 + 2*kvp     ] = (unsigned)a0[e] | ((unsigned)a1[e] << 16);
        *(unsigned*)&vlds[0][(dseg*4 + e)*34 + 2*kvp + 16] = (unsigned)b0[e] | ((unsigned)b1[e] << 16);
      }
    }
    __syncthreads();

    #pragma unroll 1
    for (int tt = 0; tt < nt; ++tt){
      int kv0 = tt * 32, cur = tt & 1;
      bool have = (tt + 1 < nt);
      u16x4 na0, na1, nb0, nb1;
      if (have){ // issue next V loads early (hide under QK/softmax)
        na0 = *(const u16x4*)(Vp + (size_t)(kv0 + 32 + 2*kvp     )*HDc + dseg*4);
        na1 = *(const u16x4*)(Vp + (size_t)(kv0 + 33 + 2*kvp     )*HDc + dseg*4);
        nb0 = *(const u16x4*)(Vp + (size_t)(kv0 + 48 + 2*kvp     )*HDc + dseg*4);
        nb1 = *(const u16x4*)(Vp + (size_t)(kv0 + 49 + 2*kvp     )*HDc + dseg*4);
      }
      // K fragments direct from global (L2-resident: 256 KB/head)
      h16x8 ka00 = *(const h16x8*)(Kp + (size_t)(kv0      + t)*HDc +      g*8);
      h16x8 ka01 = *(const h16x8*)(Kp + (size_t)(kv0      + t)*HDc + 32 + g*8);
      h16x8 ka10 = *(const h16x8*)(Kp + (size_t)(kv0 + 16 + t)*HDc +      g*8);
      h16x8 ka11 = *(const h16x8*)(Kp + (size_t)(kv0 + 16 + t)*HDc + 32 + g*8);
      f32x4 s0 = {}, s1 = {};
      s0 = mfma32(ka00, qf0, s0); s0 = mfma32(ka01, qf1, s0);
      s1 = mfma32(ka10, qf0, s1); s1 = mfma32(ka11, qf1, s1);

      float p0[4], p1[4];
      if (tt == nt - 1){ // diagonal tile: mask
        #pragma unroll
        for (int r = 0; r < 4; ++r){
          p0[r] = (kv0      + (g<<2) + r <= qrow) ? s0[r] : -1e30f;
          p1[r] = (kv0 + 16 + (g<<2) + r <= qrow) ? s1[r] : -1e30f;
        }
      } else {
        #pragma unroll
        for (int r = 0; r < 4; ++r){ p0[r] = s0[r]; p1[r] = s1[r]; }
      }
      float mt = fmaxf(fmaxf(fmaxf(p0[0],p0[1]), fmaxf(p0[2],p0[3])),
                       fmaxf(fmaxf(p1[0],p1[1]), fmaxf(p1[2],p1[3])));
      mt = fmaxf(mt, __shfl_xor(mt, 16));
      mt = fmaxf(mt, __shfl_xor(mt, 32));
      if (!__all(mt <= m_run + 8.0f)){   // T13 defer-rescale
        float m_new = fmaxf(m_run, mt);
        float alpha = exp2f(m_run - m_new);
        l_run *= alpha;
        #pragma unroll
        for (int db = 0; db < 4; ++db)
          #pragma unroll
          for (int r = 0; r < 4; ++r) o[db][r] *= alpha;
        m_run = m_new;
      }
      #pragma unroll
      for (int r = 0; r < 4; ++r){ p0[r] = exp2f(p0[r] - m_run); l_run += p0[r]; }
      #pragma unroll
      for (int r = 0; r < 4; ++r){ p1[r] = exp2f(p1[r] - m_run); l_run += p1[r]; }

      if (have){ // stage next V -> vlds[cur^1] (PV below reads vlds[cur]; no race)
        #pragma unroll
        for (int e = 0; e < 4; ++e){
          *(unsigned*)&vlds[cur^1][(dseg*4 + e)*34 + 2*kvp     ] = (unsigned)na0[e] | ((unsigned)na1[e] << 16);
          *(unsigned*)&vlds[cur^1][(dseg*4 + e)*34 + 2*kvp + 16] = (unsigned)nb0[e] | ((unsigned)nb1[e] << 16);
        }
      }

      h16x2 c0 = pkrtz(p0[0], p0[1]);
      h16x2 c1 = pkrtz(p0[2], p0[3]);
      h16x2 c2 = pkrtz(p1[0], p1[1]);
      h16x2 c3 = pkrtz(p1[2], p1[3]);
      h16x4 pf0 = {c0[0], c0[1], c1[0], c1[1]};
      h16x4 pf1 = {c2[0], c2[1], c3[0], c3[1]};
      #pragma unroll
      for (int db = 0; db < 4; ++db){
        const u16* vp = &vlds[cur][(db*16 + t)*34 + (g<<2)];
        h16x4 vf0 = *(const h16x4*)vp;
        h16x4 vf1 = *(const h16x4*)(vp + 16);
        o[db] = mfma16(vf0, pf0, o[db]);     // kv 0..15 of tile
        o[db] = mfma16(vf1, pf1, o[db]);     // kv 16..31
      }
      __syncthreads();
    }

    // final cross-g reduce of the per-lane l partials
    float lr_ = l_run;
    lr_ += __shfl_xor(lr_, 16);
    lr_ += __shfl_xor(lr_, 32);
    float inv = 1.0f / lr_;
    u16* Op = Ob + ((size_t)(b*Sc + qrow)) * Dc + hq*HDc;
    #pragma unroll
    for (int db = 0; db < 4; ++db){
      u16x4 st;
      #pragma unroll
      for (int r = 0; r < 4; ++r) st[r] = f2h(o[db][r] * inv);
      *(u16x4*)(Op + db*16 + (g<<2)) = st;
    }
  }
}

// ---------------- launch ----------------
extern "C" void kernel_launch(void* const* d_in, const int* in_sizes, int n_in,
                              void* d_out, int out_size, void* d_ws, size_t ws_size,
                              hipStream_t stream){
  const float* x    = (const float*)d_in[0];
  const float* fcos = (const float*)d_in[1];
  const float* fsin = (const float*)d_in[2];
  const float* wq   = (const float*)d_in[3];
  const float* wk   = (const float*)d_in[4];
  const float* wv   = (const float*)d_in[5];
  const float* wo   = (const float*)d_in[6];
  float* out = (float*)d_out;

  u16* ws  = (u16*)d_ws;
  u16* x16 = ws;                    // 8,388,608  (reused as attn-out Ob after gemm<0>)
  u16* wqT = x16 + 8388608;         // 4,194,304
  u16* wkT = wqT + 4194304;         // 1,048,576
  u16* wvT = wkT + 1048576;         // 1,048,576
  u16* woT = wvT + 1048576;         // 4,194,304
  u16* Qb  = woT + 4194304;         // 8,388,608
  u16* Kb  = Qb  + 8388608;         // 2,097,152
  u16* Vb  = Kb  + 2097152;         // 2,097,152
  u16* Ob  = x16;                   // alias: x16 dead after gemm<0>

  convert_x  <<<4096, 256, 0, stream>>>(x, x16);
  transpose_w<<<dim3(64,64,4), dim3(32,8), 0, stream>>>(wq, wk, wv, wo, wqT, wkT, wvT, woT);
  gemm_k<0>  <<<dim3(24,32), 256, 0, stream>>>(x16, wqT, wkT, wvT, Qb, Kb, Vb, nullptr);
  rope_k     <<<5120, 256, 0, stream>>>(Qb, Kb, fcos, fsin);
  attn_k     <<<dim3(32,64), 128, 0, stream>>>(Qb, Kb, Vb, Ob);
  gemm_k<1>  <<<dim3(16,32), 256, 0, stream>>>(Ob, woT, nullptr, nullptr, nullptr, nullptr, nullptr, out);
}